// Round 10
// baseline (298.940 us; speedup 1.0000x reference)
//
#include <hip/hip_runtime.h>
#include <hip/hip_bf16.h>

#define B_ 1024
#define IN_ 512
#define OUT_ 512
#define BTILE 32
#define OTILE 256
#define KCHUNK 8
#define KSPLIT (IN_ / KCHUNK)   // 64 k-slices

typedef float v2f __attribute__((ext_vector_type(2)));
#define PKFMA(a, b, c) __builtin_elementwise_fma((v2f)(a), (v2f)(b), (v2f)(c))

__device__ __forceinline__ float fast_exp2(float x) {
#if __has_builtin(__builtin_amdgcn_exp2f)
    return __builtin_amdgcn_exp2f(x);
#else
    return __exp2f(x);
#endif
}
__device__ __forceinline__ float fast_log2(float x) {
#if __has_builtin(__builtin_amdgcn_logf)
    return __builtin_amdgcn_logf(x);   // v_log_f32 = log2
#else
    return __log2f(x);
#endif
}
__device__ __forceinline__ float fast_cos_rev(float x) {  // cos(2*pi*x), x in revolutions
#if __has_builtin(__builtin_amdgcn_cosf)
    return __builtin_amdgcn_cosf(x);   // valid domain +-256 revs; |x| <= ~9 here
#else
    return __cosf(x * 6.2831853071795864f);
#endif
}
__device__ __forceinline__ float fast_rcp(float x) {
#if __has_builtin(__builtin_amdgcn_rcpf)
    return __builtin_amdgcn_rcpf(x);
#else
    return 1.0f / x;
#endif
}

// Thread = one o column; params for 8 i's held in ~48 VGPRs; x/silu via LDS
// broadcast (all lanes same address -> conflict-free). ONE barrier per block.
__global__ __launch_bounds__(256, 6) void chirplet_kernel(
    const float* __restrict__ x,
    const float* __restrict__ W,
    const float* __restrict__ Wc,
    const float* __restrict__ S,
    const float* __restrict__ T,
    const float* __restrict__ F,
    const float* __restrict__ bias,
    float* __restrict__ out)
{
    __shared__ __align__(16) float x_lds[KCHUNK * BTILE];   // 1 KB  [i][b]
    __shared__ __align__(16) float s_lds[KCHUNK * BTILE];   // 1 KB  silu(x)

    const int tid = threadIdx.x;
    const int o  = blockIdx.x * OTILE + tid;
    const int b0 = blockIdx.y * BTILE;
    const int ib = blockIdx.z * KCHUNK;

    const float LOG2E = 1.4426950408889634f;
    const float GK    = 0.8493218002880191f;   // sqrt(0.5*log2(e))

    // ---- stage x tile (32 b x 8 i), one element per thread, + silu
    {
        const int sb = tid >> 3;        // 0..31 (b)
        const int si = tid & 7;         // 0..7  (i) — lanes consecutive in i: coalesced 32B rows
        const float xv  = x[(size_t)(b0 + sb) * IN_ + ib + si];
        const float sig = fast_rcp(1.0f + fast_exp2(-xv * LOG2E));
        x_lds[si * BTILE + sb] = xv;
        s_lds[si * BTILE + sb] = xv * sig;
    }

    // ---- load + fold params for (o, ib..ib+7) into registers
    float pa[KCHUNK], pb[KCHUNK], pc[KCHUNK], pd[KCHUNK], plw[KCHUNK], pw[KCHUNK];
    {
        const size_t ro = (size_t)o * IN_ + ib;
        const float4 sA = *(const float4*)(S  + ro), sB = *(const float4*)(S  + ro + 4);
        const float4 tA = *(const float4*)(T  + ro), tB = *(const float4*)(T  + ro + 4);
        const float4 fA = *(const float4*)(F  + ro), fB = *(const float4*)(F  + ro + 4);
        const float4 wA = *(const float4*)(W  + ro), wB = *(const float4*)(W  + ro + 4);
        const float4 cA = *(const float4*)(Wc + ro), cB = *(const float4*)(Wc + ro + 4);
        const float sv[8] = { sA.x,sA.y,sA.z,sA.w, sB.x,sB.y,sB.z,sB.w };
        const float tv[8] = { tA.x,tA.y,tA.z,tA.w, tB.x,tB.y,tB.z,tB.w };
        const float fv[8] = { fA.x,fA.y,fA.z,fA.w, fB.x,fB.y,fB.z,fB.w };
        const float wv[8] = { wA.x,wA.y,wA.z,wA.w, wB.x,wB.y,wB.z,wB.w };
        const float cv[8] = { cA.x,cA.y,cA.z,cA.w, cB.x,cB.y,cB.z,cB.w };
        #pragma unroll
        for (int i = 0; i < KCHUNK; ++i) {
            const float rs = fast_rcp(sv[i]);
            const float a  = fv[i] * rs;                        // revolutions per x
            pa[i]  = a;
            pb[i]  = -a * tv[i] + (cv[i] < 0.0f ? 0.5f : 0.0f); // phase + sign(Wc)
            pc[i]  = rs * GK;
            pd[i]  = -tv[i] * rs * GK;
            plw[i] = fast_log2(fabsf(cv[i]));                   // log2|Wc|
            pw[i]  = wv[i];
        }
    }
    __syncthreads();   // the only barrier

    const float badd = (blockIdx.z == 0) ? bias[o] : 0.0f;

    // ---- compute: 8 b-quads x 8 i, params from regs, x/silu via LDS broadcast
    for (int bq = 0; bq < BTILE / 4; ++bq) {
        v2f acc01 = {0.f, 0.f}, acc23 = {0.f, 0.f};
        #pragma unroll
        for (int i = 0; i < KCHUNK; ++i) {
            const float4 xv = *(const float4*)&x_lds[i * BTILE + bq * 4];  // broadcast
            const float4 sl = *(const float4*)&s_lds[i * BTILE + bq * 4];  // broadcast
            const v2f x01 = { xv.x, xv.y }, x23 = { xv.z, xv.w };
            const v2f s01 = { sl.x, sl.y }, s23 = { sl.z, sl.w };
            const v2f A  = { pa[i],  pa[i]  };
            const v2f Bv = { pb[i],  pb[i]  };
            const v2f C  = { pc[i],  pc[i]  };
            const v2f D  = { pd[i],  pd[i]  };
            const v2f LW = { plw[i], plw[i] };
            const v2f Wv = { pw[i],  pw[i]  };

            v2f rev01 = PKFMA(A, x01, Bv), rev23 = PKFMA(A, x23, Bv);
            v2f u01   = PKFMA(C, x01, D),  u23   = PKFMA(C, x23, D);
            v2f g01   = PKFMA(-u01, u01, LW), g23 = PKFMA(-u23, u23, LW);
            v2f co01, co23, e01, e23;
            co01.x = fast_cos_rev(rev01.x);  co01.y = fast_cos_rev(rev01.y);
            co23.x = fast_cos_rev(rev23.x);  co23.y = fast_cos_rev(rev23.y);
            e01.x  = fast_exp2(g01.x);       e01.y  = fast_exp2(g01.y);
            e23.x  = fast_exp2(g23.x);       e23.y  = fast_exp2(g23.y);
            acc01 = PKFMA(co01, e01, acc01); acc23 = PKFMA(co23, e23, acc23);
            acc01 = PKFMA(s01, Wv, acc01);   acc23 = PKFMA(s23, Wv, acc23);
        }
        const float vals[4] = { acc01.x, acc01.y, acc23.x, acc23.y };
        #pragma unroll
        for (int j = 0; j < 4; ++j) {
            float* dst = &out[(size_t)(b0 + bq * 4 + j) * OUT_ + o];  // lanes: consecutive o -> coalesced
#if defined(__HIP_DEVICE_COMPILE__)
            unsafeAtomicAdd(dst, vals[j] + badd);   // HW global_atomic_add_f32
#else
            atomicAdd(dst, vals[j] + badd);
#endif
        }
    }
}

extern "C" void kernel_launch(void* const* d_in, const int* in_sizes, int n_in,
                              void* d_out, int out_size, void* d_ws, size_t ws_size,
                              hipStream_t stream) {
    const float* x    = (const float*)d_in[0];
    const float* W    = (const float*)d_in[1];
    const float* Wc   = (const float*)d_in[2];
    const float* S    = (const float*)d_in[3];
    const float* T    = (const float*)d_in[4];
    const float* F    = (const float*)d_in[5];
    const float* bias = (const float*)d_in[6];
    float* out = (float*)d_out;

    // d_out is poisoned before every launch; atomics need zeroed destination
    hipMemsetAsync(out, 0, (size_t)out_size * sizeof(float), stream);

    dim3 grid(OUT_ / OTILE, B_ / BTILE, KSPLIT);   // 2 x 32 x 64 = 4096 blocks
    chirplet_kernel<<<grid, 256, 0, stream>>>(x, W, Wc, S, T, F, bias, out);
}

// Round 11
// 139.715 us; speedup vs baseline: 2.1396x; 2.1396x over previous
//
#include <hip/hip_runtime.h>
#include <hip/hip_bf16.h>

#define B_ 1024
#define IN_ 512
#define OUT_ 512
#define BTILE 128
#define OTILE 32
#define ITILE 8
#define KSPLIT 32
#define KCHUNK (IN_ / KSPLIT)          // 16 i's per block
#define NCHUNKS (KCHUNK / ITILE)       // 2 staging chunks
#define P4STRIDE 128  // 32 o * 4 words; b128 writes even 8-phase (free); reads 2-way (free)
#define P2STRIDE 64   // 32 o * 2 words; reads conflict-free; writes 4-phase min (free)
#define XSTRIDE 132   // BTILE + 4 pad; mod 32 == 4 -> staging writes exactly 2-way (free)

typedef float v2f __attribute__((ext_vector_type(2)));
#define PKFMA(a, b, c) __builtin_elementwise_fma((v2f)(a), (v2f)(b), (v2f)(c))

__device__ __forceinline__ float fast_exp2(float x) {
#if __has_builtin(__builtin_amdgcn_exp2f)
    return __builtin_amdgcn_exp2f(x);
#else
    return __exp2f(x);
#endif
}
__device__ __forceinline__ float fast_log2(float x) {
#if __has_builtin(__builtin_amdgcn_logf)
    return __builtin_amdgcn_logf(x);   // v_log_f32 = log2
#else
    return __log2f(x);
#endif
}
__device__ __forceinline__ float fast_cos_rev(float x) {  // cos(2*pi*x), x in revolutions
#if __has_builtin(__builtin_amdgcn_cosf)
    return __builtin_amdgcn_cosf(x);   // valid domain +-256 revs; |x| <= ~9 here
#else
    return __cosf(x * 6.2831853071795864f);
#endif
}
__device__ __forceinline__ float fast_rcp(float x) {
#if __has_builtin(__builtin_amdgcn_rcpf)
    return __builtin_amdgcn_rcpf(x);
#else
    return 1.0f / x;
#endif
}

__global__ __launch_bounds__(256, 8) void chirplet_kernel(
    const float* __restrict__ x,
    const float* __restrict__ W,
    const float* __restrict__ Wc,
    const float* __restrict__ S,
    const float* __restrict__ T,
    const float* __restrict__ F,
    const float* __restrict__ bias,
    float* __restrict__ out)
{
    // 8b x 2o per thread: 7 LDS B/elem. ~14.5 KB LDS. Grid 16 blocks/CU queued.
    __shared__ __align__(16) float p4_lds[ITILE * P4STRIDE];  // 4 KB  {a,b',c2,d2}
    __shared__ __align__(16) float p2_lds[ITILE * P2STRIDE];  // 2 KB  {lw,w}
    __shared__ __align__(16) float x_lds[ITILE * XSTRIDE];    // 4.22 KB [i][b]
    __shared__ __align__(16) float s_lds[ITILE * XSTRIDE];    // 4.22 KB silu(x)

    const int tid = threadIdx.x;
    const int o0 = blockIdx.x * OTILE;
    const int b0 = blockIdx.y * BTILE;
    const int k0 = blockIdx.z * KCHUNK;

    // compute mapping: thread = (o pair {oc, oc+16}, 8 consecutive b)
    const int oc = tid & 15;        // 0..15
    const int bq = tid >> 4;        // 0..15 -> b = bq*8 + 0..7

    // x staging: 128 b x 8 i = 1024 floats; float4 along i, 2 threads/row
    const int xrow = tid >> 1;          // 0..127 (b)
    const int xq   = (tid & 1) * 4;     // i start

    // p staging: 32 o x 8 i = 256 entries, one per thread
    const int pol = tid & 31;           // o 0..31
    const int pi  = tid >> 5;           // i 0..7

    const float LOG2E = 1.4426950408889634f;
    const float GK    = 0.8493218002880191f;   // sqrt(0.5*log2(e))

    v2f acc[2][4] = {{{0.f,0.f},{0.f,0.f},{0.f,0.f},{0.f,0.f}},
                     {{0.f,0.f},{0.f,0.f},{0.f,0.f},{0.f,0.f}}};

    for (int c = 0; c < NCHUNKS; ++c) {
        const int ib = k0 + c * ITILE;

        // ---- stage x tile (128 b x 8 i): float4 load along i, silu, transpose
        {
            const float4 v = *(const float4*)(x + (size_t)(b0 + xrow) * IN_ + ib + xq);
            const float xf[4] = { v.x, v.y, v.z, v.w };
            #pragma unroll
            for (int j = 0; j < 4; ++j) {
                const int col = xq + j;
                float xv  = xf[j];
                float sig = fast_rcp(1.0f + fast_exp2(-xv * LOG2E));
                x_lds[col * XSTRIDE + xrow] = xv;   // 2-way banks (stride 132)
                s_lds[col * XSTRIDE + xrow] = xv * sig;
            }
        }

        // ---- stage params (32 o x 8 i), one per thread; fold coefficients.
        // sign(Wc) -> cos phase (+0.5 rev); |Wc| -> exp2 offset lw = log2|Wc|.
        {
            const size_t go = (size_t)(o0 + pol) * IN_ + ib + pi;
            const float s  = S[go];
            const float t  = T[go];
            const float f  = F[go];
            const float w  = W[go];
            const float wc = Wc[go];
            const float rs = fast_rcp(s);
            const float a  = f * rs;                       // revolutions per x
            float4 p0; float2 p1;
            p0.x = a;
            p0.y = -a * t + (wc < 0.0f ? 0.5f : 0.0f);     // phase offset + sign(Wc)
            p0.z = rs * GK;
            p0.w = -t * rs * GK;
            p1.x = fast_log2(fabsf(wc));                   // lw
            p1.y = w;
            *(float4*)&p4_lds[pi * P4STRIDE + pol * 4] = p0;
            *(float2*)&p2_lds[pi * P2STRIDE + pol * 2] = p1;
        }
        __syncthreads();

        // ---- compute: 8 b x 2 o per thread over ITILE i's (7 LDS B/elem)
        #pragma unroll 2
        for (int i = 0; i < ITILE; ++i) {
            const v2f* xp = (const v2f*)&x_lds[i * XSTRIDE + bq * 8];
            const v2f* sp = (const v2f*)&s_lds[i * XSTRIDE + bq * 8];
            const v2f xk[4] = { xp[0], xp[1], xp[2], xp[3] };
            const v2f sk[4] = { sp[0], sp[1], sp[2], sp[3] };
            #pragma unroll
            for (int o = 0; o < 2; ++o) {
                const float4 p0 = *(const float4*)&p4_lds[i * P4STRIDE + (oc + o * 16) * 4];
                const float2 p1 = *(const float2*)&p2_lds[i * P2STRIDE + (oc + o * 16) * 2];
                const v2f A  = { p0.x, p0.x };
                const v2f Bv = { p0.y, p0.y };
                const v2f C  = { p0.z, p0.z };
                const v2f D  = { p0.w, p0.w };
                const v2f LW = { p1.x, p1.x };
                const v2f Wv = { p1.y, p1.y };
                #pragma unroll
                for (int p = 0; p < 4; ++p) {
                    v2f rev = PKFMA(A, xk[p], Bv);        // phase (revs)
                    v2f u   = PKFMA(C, xk[p], D);         // GK*(x-t)/s
                    v2f g   = PKFMA(-u, u, LW);           // lw - u^2
                    v2f co, e;
                    co.x = fast_cos_rev(rev.x);
                    co.y = fast_cos_rev(rev.y);
                    e.x  = fast_exp2(g.x);
                    e.y  = fast_exp2(g.y);
                    acc[o][p] = PKFMA(co, e, acc[o][p]);  // chirplet
                    acc[o][p] = PKFMA(sk[p], Wv, acc[o][p]); // silu*W
                }
            }
        }
        __syncthreads();
    }

    // ---- epilogue: bias (once, from kslice 0) + fp32 atomic accumulate
    #pragma unroll
    for (int o = 0; o < 2; ++o) {
        const float badd = (blockIdx.z == 0) ? bias[o0 + oc + o * 16] : 0.0f;
        #pragma unroll
        for (int p = 0; p < 4; ++p) {
            #pragma unroll
            for (int j = 0; j < 2; ++j) {
                const int b = b0 + bq * 8 + p * 2 + j;
                float* dst = &out[(size_t)b * OUT_ + o0 + oc + o * 16];
                const float val = (j == 0 ? acc[o][p].x : acc[o][p].y) + badd;
#if defined(__HIP_DEVICE_COMPILE__)
                unsafeAtomicAdd(dst, val);   // HW global_atomic_add_f32
#else
                atomicAdd(dst, val);
#endif
            }
        }
    }
}

extern "C" void kernel_launch(void* const* d_in, const int* in_sizes, int n_in,
                              void* d_out, int out_size, void* d_ws, size_t ws_size,
                              hipStream_t stream) {
    const float* x    = (const float*)d_in[0];
    const float* W    = (const float*)d_in[1];
    const float* Wc   = (const float*)d_in[2];
    const float* S    = (const float*)d_in[3];
    const float* T    = (const float*)d_in[4];
    const float* F    = (const float*)d_in[5];
    const float* bias = (const float*)d_in[6];
    float* out = (float*)d_out;

    // d_out is poisoned before every launch; atomics need zeroed destination
    hipMemsetAsync(out, 0, (size_t)out_size * sizeof(float), stream);

    dim3 grid(OUT_ / OTILE, B_ / BTILE, KSPLIT);   // 16 x 8 x 32 = 4096 blocks
    chirplet_kernel<<<grid, 256, 0, stream>>>(x, W, Wc, S, T, F, bias, out);
}